// Round 1
// 117.701 us; speedup vs baseline: 1.0497x; 1.0497x over previous
//
#include <hip/hip_runtime.h>
#include <stdint.h>

// ---------------------------------------------------------------------------
// B=2048, F0=40, D=32, LAYER0=LAYER1=128.  Rows r=b*32+d (65536).
//   phase0: h0[r,s] = relu(sum_{i<40,j<40} X[r,i]X[r,j] W0[i,j,s] + b0[s])
//   phase1: d1[r,s] = relu(sum_{i<40,j<64} X[r,i]NH[r,j] W1[i,j,s] + b1[s])
//   out[b,0:64] = sum_d h0[:,64:128]; out[b,64:192] = sum_d d1
//
// Round-10 changes vs round-9 (67us fused, MfmaUtil 42%, 4.67M LDS conflicts):
//  (a) CONFLICT-FREE W LAYOUT.  Old tile layout [s=128][k=32] made the bv
//      ds_read_b128 a lane<->addr transpose (lane=kc*16+ml read ml*64+kc*16):
//      ~4-way bank conflict, 4.4 extra cyc/read (= the 4.67M counter), LDS
//      pipe busy ~= MFMA pipe busy -> pipes serialize at 2 waves/SIMD.
//      New tile layout [sh][nt][lane][k-oct]: read addr = base + lane*16B,
//      lane-linear contiguous -> 0 conflicts.  Identity DMA staging preserved
//      (global layout == LDS layout == read order).
//  (b) SYMMETRIZED W0.  Quadratic form: fold W0 into Wsym = W0+W0^T on the
//      upper triangle (diag kept, lower zeroed) and DROP the 20/50 tiles that
//      are entirely lower-triangle (keep (ic,jc) iff ic<=2*jc+1 -> 30 tiles).
//      Exact math; phase0 MFMA/LDS/DMA -40%, total MFMA -15.4%.
//      Triangular schedule is compile-time: jc blocks {2,4,6,8,10} tiles,
//      jv reloads at t=0,2,6,12,20 (two of them mid-period, negligible).
// Everything else (5-tile periods, global_load_lds w16 double-buffer, one
// barrier per period, fp16 datapath, epilogues) unchanged.
// ---------------------------------------------------------------------------

typedef __attribute__((ext_vector_type(8))) _Float16 half8;
typedef __attribute__((ext_vector_type(2))) _Float16 half2v;
typedef __attribute__((ext_vector_type(4))) float f32x4;

#define T0 30        // phase0 tiles after triangular drop (was 50)
#define T1 80        // phase1 tiles
#define WBUF 20480   // halfwords per Wb buffer (5 tiles x 4096)

// phase-0 triangular schedule: jc blocks of sizes 2,4,6,8,10 (starts 0,2,6,12,20)
__host__ __device__ constexpr int ic0_of(int t) {
    return (t < 2) ? t : (t < 6) ? (t - 2) : (t < 12) ? (t - 6)
         : (t < 20) ? (t - 12) : (t - 20);
}
__host__ __device__ constexpr int jc0_of(int t) {
    return (t < 2) ? 0 : (t < 6) ? 1 : (t < 12) ? 2 : (t < 20) ? 3 : 4;
}

__device__ __forceinline__ unsigned short f2h(float f) {   // v_cvt_f16_f32, RNE
    return __builtin_bit_cast(unsigned short, (_Float16)f);
}
__device__ __forceinline__ float qsum(float v) {  // reduce across row-quads
    v += __shfl_xor(v, 16, 64);
    v += __shfl_xor(v, 32, 64);
    return v;
}
// async global->LDS DMA, 16 B/lane.  lds dest = (wave-uniform base) + lane*16.
__device__ __forceinline__ void gl_lds16(const unsigned short* g, unsigned short* l) {
    __builtin_amdgcn_global_load_lds(
        (const __attribute__((address_space(1))) unsigned int*)g,
        (__attribute__((address_space(3))) unsigned int*)l,
        16, 0, 0);
}

// ---------------------------------------------------------------------------
// Permute W -> Wp[t][ halfword pos = sh*2048 + nt*512 + lane*8 + oc ], where
// lane = kc*16+ml encodes (s = sh*64+nt*16+ml, k-octet kc), oc = k within
// octet.  Element value = W[i = ic*4+kc][j = jc*8+oc][s].  This is EXACTLY
// the order the compute wave reads (16B per lane, lane-linear) -> conflict-
// free ds_read_b128 AND identity global_load_lds staging.
// Phase0 tiles get the symmetrized, triangular-dropped Wsym.
// One block per tile (110 blocks), 256 threads x 16 halfwords.
// ---------------------------------------------------------------------------
__global__ void permute_w_both(const float* __restrict__ W0, const float* __restrict__ W1,
                               unsigned short* __restrict__ Wp0, unsigned short* __restrict__ Wp1)
{
    const int t = blockIdx.x;
    const int tid = threadIdx.x;
    unsigned short outv[16];
    unsigned short* dst;
    if (t < T0) {
        const int ic = ic0_of(t), jc = jc0_of(t);
        #pragma unroll
        for (int q = 0; q < 16; ++q) {
            int pos  = tid * 16 + q;
            int oc   = pos & 7, lane = (pos >> 3) & 63;
            int nt   = (pos >> 9) & 3, sh = pos >> 11;
            int s    = sh * 64 + nt * 16 + (lane & 15);
            int i    = ic * 4 + (lane >> 4), j = jc * 8 + oc;
            float v = 0.0f;                                   // i>j: folded into (j,i)
            if (i < j)       v = W0[((size_t)(i * 40 + j)) * 128 + s]
                               + W0[((size_t)(j * 40 + i)) * 128 + s];
            else if (i == j) v = W0[((size_t)(i * 40 + i)) * 128 + s];
            outv[q] = f2h(v);
        }
        dst = Wp0 + (size_t)t * 4096 + tid * 16;
    } else {
        const int tt = t - T0;
        const int jc = tt / 10, ic = tt % 10;
        #pragma unroll
        for (int q = 0; q < 16; ++q) {
            int pos  = tid * 16 + q;
            int oc   = pos & 7, lane = (pos >> 3) & 63;
            int nt   = (pos >> 9) & 3, sh = pos >> 11;
            int s    = sh * 64 + nt * 16 + (lane & 15);
            int i    = ic * 4 + (lane >> 4), j = jc * 8 + oc;
            outv[q] = f2h(W1[((size_t)(i * 64 + j)) * 128 + s]);
        }
        dst = Wp1 + (size_t)tt * 4096 + tid * 16;
    }
    *(uint4*)dst       = *(const uint4*)outv;
    *(uint4*)(dst + 8) = *(const uint4*)(outv + 8);
}

// One GEMM phase.  Flat compile-time tile schedule (ic/jc per t), 5-tile
// periods, W staged in LDS via global_load_lds (double-buffered periods),
// one barrier per period.  jv reloaded whenever jc changes (compile-time).
template<int T, int PHASE>
__device__ __forceinline__ void gemm_phase(
    const unsigned short* __restrict__ Wp,   // [T][4096] fp16, global, read-order layout
    const unsigned short* __restrict__ Jl,   // LDS j-source (Xl or NH)
    int jstride,                             // row stride of Jl in elems
    const unsigned int xi2[4][10],           // broadcast half2 of X[r, ic*4+kc]
    unsigned short* Wb,                      // LDS W double buffer [2][WBUF]
    f32x4 acc[4][4], int tid)
{
    const int lane = tid & 63;
    const int wv = tid >> 6;                 // wave id 0..7
    const int rt = wv & 3;                   // row-tile (64 rows)
    const int sh = tid >> 8;                 // s-half (64 cols)
    const int ml = lane & 15;

    const unsigned short* jrow[4];
    #pragma unroll
    for (int mt = 0; mt < 4; ++mt)
        jrow[mt] = Jl + (rt * 64 + mt * 16 + ml) * jstride;

    // conflict-free bv base: per-(sh,nt) 1KB chunk, addr = base + lane*16B
    const unsigned short* brd = Wb + sh * 2048 + lane * 8;
    // DMA: global src per-lane = Wp + tile*4096 + tid*8 (halfwords);
    //      LDS dest wave-uniform = Wb + buf*WBUF + u*4096 + wv*512.
    const unsigned short* gsrc = Wp + tid * 8;
    unsigned short* ldst = Wb + wv * 512;

    auto stage_period = [&](int buf, int t0) {   // issue 5 tile DMAs
        #pragma unroll
        for (int u = 0; u < 5; ++u)
            gl_lds16(gsrc + (size_t)(t0 + u) * 4096, ldst + buf * WBUF + u * 4096);
    };

    stage_period(0, 0);          // period 0 -> buf0
    __syncthreads();             // tiles landed

    uint4 jv[4];
    constexpr int NP = T / 5;
    #pragma unroll
    for (int p = 0; p < NP; ++p) {
        const int cb = p & 1;                            // compute buffer
        const int nb = cb ^ 1;
        if ((p + 1) * 5 < T) stage_period(nb, (p + 1) * 5);  // full period to land
        #pragma unroll
        for (int u = 0; u < 5; ++u) {
            const int t  = p * 5 + u;                    // compile-time
            const int ic = (PHASE == 0) ? ic0_of(t) : (t % 10);
            const int jc = (PHASE == 0) ? jc0_of(t) : (t / 10);
            const bool rl = (t == 0) ||
                (jc != ((PHASE == 0) ? jc0_of(t - 1) : ((t - 1) / 10)));
            if (rl) {                                    // jv reload (jc changed)
                #pragma unroll
                for (int mt = 0; mt < 4; ++mt)
                    jv[mt] = *(const uint4*)(jrow[mt] + jc * 8);
            }
            uint4 bv[4];
            #pragma unroll
            for (int nt = 0; nt < 4; ++nt)               // lane-linear: 0 conflicts
                bv[nt] = *(const uint4*)(brd + cb * WBUF + u * 4096 + nt * 512);
            uint4 av[4];
            #pragma unroll
            for (int mt = 0; mt < 4; ++mt) {
                half2v x2 = __builtin_bit_cast(half2v, xi2[mt][ic]);
                av[mt].x = __builtin_bit_cast(unsigned int,
                    (half2v)(x2 * __builtin_bit_cast(half2v, jv[mt].x)));
                av[mt].y = __builtin_bit_cast(unsigned int,
                    (half2v)(x2 * __builtin_bit_cast(half2v, jv[mt].y)));
                av[mt].z = __builtin_bit_cast(unsigned int,
                    (half2v)(x2 * __builtin_bit_cast(half2v, jv[mt].z)));
                av[mt].w = __builtin_bit_cast(unsigned int,
                    (half2v)(x2 * __builtin_bit_cast(half2v, jv[mt].w)));
            }
            #pragma unroll
            for (int mt = 0; mt < 4; ++mt)
                #pragma unroll
                for (int nt = 0; nt < 4; ++nt)
                    acc[mt][nt] = __builtin_amdgcn_mfma_f32_16x16x32_f16(
                        __builtin_bit_cast(half8, av[mt]),
                        __builtin_bit_cast(half8, bv[nt]),
                        acc[mt][nt], 0, 0, 0);
        }
        __syncthreads();     // nb DMA landed; cb reads done
    }
}

__global__ __launch_bounds__(512, 2)
void fused_two_layer(const float* __restrict__ x,
                     const unsigned short* __restrict__ W0p,
                     const float* __restrict__ b0,
                     const unsigned short* __restrict__ W1p,
                     const float* __restrict__ b1,
                     float* __restrict__ out)
{
    __shared__ __align__(16) unsigned short Xl[256 * 40];   // 20.0 KB
    __shared__ __align__(16) unsigned short NH[256 * 72];   // 36.9 KB (stride 72
        // -> 144B rows: b128 j-reads 2-way max = free)
    __shared__ __align__(16) unsigned short Wb[2 * WBUF];   // 80.0 KB W dbuf

    const int tid  = threadIdx.x;
    const int lane = tid & 63;
    const int rt   = (tid >> 6) & 3;    // row-tile (64 rows)
    const int sh   = tid >> 8;          // s-half (64 cols)
    const int ml   = lane & 15;
    const int kc   = lane >> 4;

    // ---- stage X: x[8b][i][d] fp32 -> Xl[(bl*32+d)*40 + i] fp16 (RNE) ----
    const float* xblk = x + (size_t)blockIdx.x * (8 * 40 * 32);
    #pragma unroll
    for (int bl = 0; bl < 8; ++bl) {
        #pragma unroll
        for (int k = 0; k < 3; ++k) {
            int f = 512 * k + tid;
            if (f < 1280) {
                int i = f >> 5, d = f & 31;
                Xl[(bl * 32 + d) * 40 + i] = f2h(xblk[bl * 1280 + f]);
            }
        }
    }
    __syncthreads();

    // ---- preload this lane's i-scalars as broadcast half2 (both phases) ----
    unsigned int xi2[4][10];
    #pragma unroll
    for (int mt = 0; mt < 4; ++mt) {
        const unsigned short* xr = Xl + (rt * 64 + mt * 16 + ml) * 40;
        #pragma unroll
        for (int ic = 0; ic < 10; ++ic) {
            unsigned int u = xr[ic * 4 + kc];
            xi2[mt][ic] = u | (u << 16);
        }
    }

    f32x4 acc[4][4];
    const f32x4 zero4 = {0.f, 0.f, 0.f, 0.f};
    #pragma unroll
    for (int mt = 0; mt < 4; ++mt)
        #pragma unroll
        for (int nt = 0; nt < 4; ++nt) acc[mt][nt] = zero4;

    // ========== phase 0: 30 triangular tiles (Wsym), j from X ==========
    gemm_phase<T0, 0>(W0p, Xl, 40, xi2, Wb, acc, tid);

    {   // epilogue 0: bias+relu; sh==0 (s<64) -> NH; sh==1 -> d-sum -> out[:,0:64]
        float bias[4];
        #pragma unroll
        for (int nt = 0; nt < 4; ++nt) bias[nt] = b0[sh * 64 + nt * 16 + ml];
        if (sh == 0) {
            #pragma unroll
            for (int mt = 0; mt < 4; ++mt) {
                int r = rt * 64 + mt * 16 + (kc << 2);
                #pragma unroll
                for (int nt = 0; nt < 4; ++nt) {
                    int s = nt * 16 + ml;
                    #pragma unroll
                    for (int rg = 0; rg < 4; ++rg) {
                        float v = fmaxf(acc[mt][nt][rg] + bias[nt], 0.0f);
                        NH[(r + rg) * 72 + s] = f2h(v);
                    }
                }
            }
        } else {
            int bb = blockIdx.x * 8 + rt * 2;
            #pragma unroll
            for (int nt = 0; nt < 4; ++nt) {
                float sA = 0.f, sB = 0.f;
                #pragma unroll
                for (int rg = 0; rg < 4; ++rg) {
                    sA += fmaxf(acc[0][nt][rg] + bias[nt], 0.f) + fmaxf(acc[1][nt][rg] + bias[nt], 0.f);
                    sB += fmaxf(acc[2][nt][rg] + bias[nt], 0.f) + fmaxf(acc[3][nt][rg] + bias[nt], 0.f);
                }
                sA = qsum(sA); sB = qsum(sB);
                if (lane < 16) {
                    int col = nt * 16 + lane;        // s-64
                    out[(size_t)bb * 192 + col]       = sA;
                    out[(size_t)(bb + 1) * 192 + col] = sB;
                }
            }
        }
    }
    __syncthreads();   // NH visible to all waves

    #pragma unroll
    for (int mt = 0; mt < 4; ++mt)
        #pragma unroll
        for (int nt = 0; nt < 4; ++nt) acc[mt][nt] = zero4;

    // ================= phase 1: 80 tiles, j from NH ================
    gemm_phase<T1, 1>(W1p, NH, 72, xi2, Wb, acc, tid);

    {   // epilogue 1: bias+relu; d-sum -> out[:, 64:192]
        float bias[4];
        #pragma unroll
        for (int nt = 0; nt < 4; ++nt) bias[nt] = b1[sh * 64 + nt * 16 + ml];
        int bb = blockIdx.x * 8 + rt * 2;
        #pragma unroll
        for (int nt = 0; nt < 4; ++nt) {
            float sA = 0.f, sB = 0.f;
            #pragma unroll
            for (int rg = 0; rg < 4; ++rg) {
                sA += fmaxf(acc[0][nt][rg] + bias[nt], 0.f) + fmaxf(acc[1][nt][rg] + bias[nt], 0.f);
                sB += fmaxf(acc[2][nt][rg] + bias[nt], 0.f) + fmaxf(acc[3][nt][rg] + bias[nt], 0.f);
            }
            sA = qsum(sA); sB = qsum(sB);
            if (lane < 16) {
                int col = 64 + sh * 64 + nt * 16 + lane;
                out[(size_t)bb * 192 + col]       = sA;
                out[(size_t)(bb + 1) * 192 + col] = sB;
            }
        }
    }
}

extern "C" void kernel_launch(void* const* d_in, const int* in_sizes, int n_in,
                              void* d_out, int out_size, void* d_ws, size_t ws_size,
                              hipStream_t stream) {
    const float* x  = (const float*)d_in[0];   // [2048][40][32]
    const float* W0 = (const float*)d_in[1];   // [40][40][128]
    const float* b0 = (const float*)d_in[2];   // [128]
    const float* W1 = (const float*)d_in[3];   // [40][64][128]
    const float* b1 = (const float*)d_in[4];   // [128]
    float* out = (float*)d_out;                // [2048][192]

    unsigned short* W0p = (unsigned short*)d_ws;                          // T0*4096*2 = 245760 B
    unsigned short* W1p = (unsigned short*)((char*)d_ws + T0 * 4096 * 2); // T1*4096*2 = 655360 B

    permute_w_both<<<T0 + T1, 256, 0, stream>>>(W0, W1, W0p, W1p);
    fused_two_layer<<<256, 512, 0, stream>>>(x, W0p, b0, W1p, b1, out);
}

// Round 2
// 116.814 us; speedup vs baseline: 1.0577x; 1.0076x over previous
//
#include <hip/hip_runtime.h>
#include <stdint.h>

// ---------------------------------------------------------------------------
// B=2048, F0=40, D=32, LAYER0=LAYER1=128.  Rows r=b*32+d (65536).
//   phase0: h0[r,s] = relu(sum_{i<40,j<40} X[r,i]X[r,j] W0[i,j,s] + b0[s])
//   phase1: d1[r,s] = relu(sum_{i<40,j<64} X[r,i]NH[r,j] W1[i,j,s] + b1[s])
//   out[b,0:64] = sum_d h0[:,64:128]; out[b,64:192] = sum_d d1
//
// Round-11: OCCUPANCY.  r10 (55us) showed MfmaUtil 42% / VALUBusy 26% /
// Occupancy 20% with conflicts fixed -> latency/occupancy-bound: 1 block/CU
// = 2 lockstep waves/SIMD; every period's vmcnt(0)+barrier and every VALU
// burst (A-frag pack, jv, epilogue) stalls the whole SIMD.
// Fix: 2 independent blocks/CU.  Block = 128 rows (4 batch elems), 512 thr
// = 8 waves (4 row-tiles x 32 rows, 2 s-halves), acc[2][4]/wave.  W dbuf
// shrinks to 3-tile periods: LDS = 10+18+48 = 76KB -> 2 blocks co-resident
// (152.6 <= 160KB).  4 waves/SIMD from two DESYNCED blocks: one block's
// barrier drain hides under the other's MFMA stream.  Phase1 pads 80->81
// tiles (zero W tile; its jv reads NH cols 64..71 which are zeroed).
// W L2 traffic x2 (465MB, ~12 TB/s agg << 34.5 L2 ceiling).
// Carried from r10: conflict-free W layout [sh][nt][lane][oct] (identity
// global_load_lds staging, lane-linear ds_read_b128), symmetrized W0 with
// triangular tile drop (30 tiles: jc blocks 2,4,6,8,10), fp16 datapath.
// ---------------------------------------------------------------------------

typedef __attribute__((ext_vector_type(8))) _Float16 half8;
typedef __attribute__((ext_vector_type(2))) _Float16 half2v;
typedef __attribute__((ext_vector_type(4))) float f32x4;

#define T0 30        // phase0 tiles after triangular drop
#define T1P 81       // phase1 tiles incl. 1 zero pad tile (80 real)
#define PERIOD 3
#define WBUF 12288   // halfwords per Wb buffer (3 tiles x 4096)

// phase-0 triangular schedule: jc blocks of sizes 2,4,6,8,10 (starts 0,2,6,12,20)
__host__ __device__ constexpr int ic0_of(int t) {
    return (t < 2) ? t : (t < 6) ? (t - 2) : (t < 12) ? (t - 6)
         : (t < 20) ? (t - 12) : (t - 20);
}
__host__ __device__ constexpr int jc0_of(int t) {
    return (t < 2) ? 0 : (t < 6) ? 1 : (t < 12) ? 2 : (t < 20) ? 3 : 4;
}

__device__ __forceinline__ unsigned short f2h(float f) {   // v_cvt_f16_f32, RNE
    return __builtin_bit_cast(unsigned short, (_Float16)f);
}
__device__ __forceinline__ float qsum(float v) {  // reduce across row-quads
    v += __shfl_xor(v, 16, 64);
    v += __shfl_xor(v, 32, 64);
    return v;
}
// async global->LDS DMA, 16 B/lane.  lds dest = (wave-uniform base) + lane*16.
__device__ __forceinline__ void gl_lds16(const unsigned short* g, unsigned short* l) {
    __builtin_amdgcn_global_load_lds(
        (const __attribute__((address_space(1))) unsigned int*)g,
        (__attribute__((address_space(3))) unsigned int*)l,
        16, 0, 0);
}

// ---------------------------------------------------------------------------
// Permute W -> Wp[t][ halfword pos = sh*2048 + nt*512 + lane*8 + oc ], where
// lane = kc*16+ml encodes (s = sh*64+nt*16+ml, k-octet kc), oc = k within
// octet.  Element = W[i = ic*4+kc][j = jc*8+oc][s].  Exactly the compute
// read order (16B/lane, lane-linear) -> conflict-free ds_read_b128 AND
// identity global_load_lds staging.  Phase0 tiles: symmetrized triangular
// Wsym.  Phase1 tile 80 = zeros (pad).  111 blocks x 256 threads.
// ---------------------------------------------------------------------------
__global__ void permute_w_both(const float* __restrict__ W0, const float* __restrict__ W1,
                               unsigned short* __restrict__ Wp0, unsigned short* __restrict__ Wp1)
{
    const int t = blockIdx.x;
    const int tid = threadIdx.x;
    unsigned short outv[16];
    unsigned short* dst;
    if (t < T0) {
        const int ic = ic0_of(t), jc = jc0_of(t);
        #pragma unroll
        for (int q = 0; q < 16; ++q) {
            int pos  = tid * 16 + q;
            int oc   = pos & 7, lane = (pos >> 3) & 63;
            int nt   = (pos >> 9) & 3, sh = pos >> 11;
            int s    = sh * 64 + nt * 16 + (lane & 15);
            int i    = ic * 4 + (lane >> 4), j = jc * 8 + oc;
            float v = 0.0f;                                   // i>j: folded into (j,i)
            if (i < j)       v = W0[((size_t)(i * 40 + j)) * 128 + s]
                               + W0[((size_t)(j * 40 + i)) * 128 + s];
            else if (i == j) v = W0[((size_t)(i * 40 + i)) * 128 + s];
            outv[q] = f2h(v);
        }
        dst = Wp0 + (size_t)t * 4096 + tid * 16;
    } else {
        const int tt = t - T0;
        if (tt == 80) {                                       // zero pad tile
            #pragma unroll
            for (int q = 0; q < 16; ++q) outv[q] = 0;
        } else {
            const int jc = tt / 10, ic = tt % 10;
            #pragma unroll
            for (int q = 0; q < 16; ++q) {
                int pos  = tid * 16 + q;
                int oc   = pos & 7, lane = (pos >> 3) & 63;
                int nt   = (pos >> 9) & 3, sh = pos >> 11;
                int s    = sh * 64 + nt * 16 + (lane & 15);
                int i    = ic * 4 + (lane >> 4), j = jc * 8 + oc;
                outv[q] = f2h(W1[((size_t)(i * 64 + j)) * 128 + s]);
            }
        }
        dst = Wp1 + (size_t)tt * 4096 + tid * 16;
    }
    *(uint4*)dst       = *(const uint4*)outv;
    *(uint4*)(dst + 8) = *(const uint4*)(outv + 8);
}

// One GEMM phase.  Flat compile-time tile schedule, 3-tile periods, W staged
// via global_load_lds (double-buffered periods), one barrier per period.
// Phase1 t=80 is the pad: ic=0, jc=8 fall out of t%10 / t/10 naturally; its
// jv reads NH cols 64..71 (zeroed) -> exact zero contribution.
template<int T, int PHASE>
__device__ __forceinline__ void gemm_phase(
    const unsigned short* __restrict__ Wp,   // [T][4096] fp16, global, read-order layout
    const unsigned short* __restrict__ Jl,   // LDS j-source (Xl or NH)
    int jstride,                             // row stride of Jl in elems
    const unsigned int xi2[2][10],           // broadcast half2 of X[r, ic*4+kc]
    unsigned short* Wb,                      // LDS W double buffer [2][WBUF]
    f32x4 acc[2][4], int tid)
{
    const int lane = tid & 63;
    const int wv = tid >> 6;                 // wave id 0..7
    const int rt = wv & 3;                   // row-tile (32 rows)
    const int sh = wv >> 2;                  // s-half (64 cols)
    const int ml = lane & 15;

    const unsigned short* jrow[2];
    #pragma unroll
    for (int mt = 0; mt < 2; ++mt)
        jrow[mt] = Jl + (rt * 32 + mt * 16 + ml) * jstride;

    // conflict-free bv base: per-(sh,nt) 1KB chunk, addr = base + lane*16B
    const unsigned short* brd = Wb + sh * 2048 + lane * 8;
    // DMA: global src per-lane = Wp + tile*4096 + tid*8 (halfwords);
    //      LDS dest wave-uniform = Wb + buf*WBUF + u*4096 + wv*512.
    const unsigned short* gsrc = Wp + tid * 8;
    unsigned short* ldst = Wb + wv * 512;

    auto stage_period = [&](int buf, int t0) {   // issue 3 tile DMAs
        #pragma unroll
        for (int u = 0; u < PERIOD; ++u)
            gl_lds16(gsrc + (size_t)(t0 + u) * 4096, ldst + buf * WBUF + u * 4096);
    };

    stage_period(0, 0);          // period 0 -> buf0
    __syncthreads();             // tiles landed

    uint4 jv[2];
    constexpr int NP = T / PERIOD;
    #pragma unroll
    for (int p = 0; p < NP; ++p) {
        const int cb = p & 1;                            // compute buffer
        const int nb = cb ^ 1;
        if ((p + 1) * PERIOD < T) stage_period(nb, (p + 1) * PERIOD);
        #pragma unroll
        for (int u = 0; u < PERIOD; ++u) {
            const int t  = p * PERIOD + u;               // compile-time
            const int ic = (PHASE == 0) ? ic0_of(t) : (t % 10);
            const int jc = (PHASE == 0) ? jc0_of(t) : (t / 10);
            const bool rl = (t == 0) ||
                (jc != ((PHASE == 0) ? jc0_of(t - 1) : ((t - 1) / 10)));
            if (rl) {                                    // jv reload (jc changed)
                #pragma unroll
                for (int mt = 0; mt < 2; ++mt)
                    jv[mt] = *(const uint4*)(jrow[mt] + jc * 8);
            }
            uint4 bv[4];
            #pragma unroll
            for (int nt = 0; nt < 4; ++nt)               // lane-linear: 0 conflicts
                bv[nt] = *(const uint4*)(brd + cb * WBUF + u * 4096 + nt * 512);
            uint4 av[2];
            #pragma unroll
            for (int mt = 0; mt < 2; ++mt) {
                half2v x2 = __builtin_bit_cast(half2v, xi2[mt][ic]);
                av[mt].x = __builtin_bit_cast(unsigned int,
                    (half2v)(x2 * __builtin_bit_cast(half2v, jv[mt].x)));
                av[mt].y = __builtin_bit_cast(unsigned int,
                    (half2v)(x2 * __builtin_bit_cast(half2v, jv[mt].y)));
                av[mt].z = __builtin_bit_cast(unsigned int,
                    (half2v)(x2 * __builtin_bit_cast(half2v, jv[mt].z)));
                av[mt].w = __builtin_bit_cast(unsigned int,
                    (half2v)(x2 * __builtin_bit_cast(half2v, jv[mt].w)));
            }
            #pragma unroll
            for (int mt = 0; mt < 2; ++mt)
                #pragma unroll
                for (int nt = 0; nt < 4; ++nt)
                    acc[mt][nt] = __builtin_amdgcn_mfma_f32_16x16x32_f16(
                        __builtin_bit_cast(half8, av[mt]),
                        __builtin_bit_cast(half8, bv[nt]),
                        acc[mt][nt], 0, 0, 0);
        }
        __syncthreads();     // nb DMA landed; cb reads done
    }
}

__global__ __launch_bounds__(512, 4)
void fused_two_layer(const float* __restrict__ x,
                     const unsigned short* __restrict__ W0p,
                     const float* __restrict__ b0,
                     const unsigned short* __restrict__ W1p,
                     const float* __restrict__ b1,
                     float* __restrict__ out)
{
    __shared__ __align__(16) unsigned short Xl[128 * 40];   // 10.0 KB
    __shared__ __align__(16) unsigned short NH[128 * 72];   // 18.0 KB (stride 72
        // -> 144B rows: b128 j-reads 2-way max = free; cols 64..71 zero pad)
    __shared__ __align__(16) unsigned short Wb[2 * WBUF];   // 48.0 KB W dbuf
    // total 76.0 KB -> 2 blocks/CU

    const int tid  = threadIdx.x;
    const int lane = tid & 63;
    const int wv   = tid >> 6;
    const int rt   = wv & 3;            // row-tile (32 rows)
    const int sh   = wv >> 2;           // s-half (64 cols)
    const int ml   = lane & 15;
    const int kc   = lane >> 4;

    // ---- stage X: x[4b][i][d] fp32 -> Xl[(bl*32+d)*40 + i] fp16 (RNE) ----
    const float* xblk = x + (size_t)blockIdx.x * (4 * 40 * 32);
    #pragma unroll
    for (int k = 0; k < 10; ++k) {
        int f = 512 * k + tid;          // 0..5119, coalesced
        int bl = f / 1280, rem = f - bl * 1280;
        int i = rem >> 5, d = rem & 31;
        Xl[(bl * 32 + d) * 40 + i] = f2h(xblk[f]);
    }
    __syncthreads();

    // ---- preload this lane's i-scalars as broadcast half2 (both phases) ----
    unsigned int xi2[2][10];
    #pragma unroll
    for (int mt = 0; mt < 2; ++mt) {
        const unsigned short* xr = Xl + (rt * 32 + mt * 16 + ml) * 40;
        #pragma unroll
        for (int ic = 0; ic < 10; ++ic) {
            unsigned int u = xr[ic * 4 + kc];
            xi2[mt][ic] = u | (u << 16);
        }
    }

    f32x4 acc[2][4];
    const f32x4 zero4 = {0.f, 0.f, 0.f, 0.f};
    #pragma unroll
    for (int mt = 0; mt < 2; ++mt)
        #pragma unroll
        for (int nt = 0; nt < 4; ++nt) acc[mt][nt] = zero4;

    // ========== phase 0: 30 triangular tiles (Wsym), j from X ==========
    gemm_phase<T0, 0>(W0p, Xl, 40, xi2, Wb, acc, tid);

    {   // epilogue 0: bias+relu; sh==0 (s<64) -> NH; sh==1 -> d-sum -> out[:,0:64]
        float bias[4];
        #pragma unroll
        for (int nt = 0; nt < 4; ++nt) bias[nt] = b0[sh * 64 + nt * 16 + ml];
        if (sh == 0) {
            #pragma unroll
            for (int mt = 0; mt < 2; ++mt) {
                int r = rt * 32 + mt * 16 + (kc << 2);
                #pragma unroll
                for (int nt = 0; nt < 4; ++nt) {
                    int s = nt * 16 + ml;
                    #pragma unroll
                    for (int rg = 0; rg < 4; ++rg) {
                        float v = fmaxf(acc[mt][nt][rg] + bias[nt], 0.0f);
                        NH[(r + rg) * 72 + s] = f2h(v);
                    }
                }
            }
            // zero NH pad cols 64..71 for this wave's 32 rows (jc=8 pad tile)
            {
                int rp = rt * 32 + (lane >> 1);
                int a  = rp * 72 + 64 + (lane & 1) * 4;
                *(unsigned int*)&NH[a]     = 0u;
                *(unsigned int*)&NH[a + 2] = 0u;
            }
        } else {
            int bb = blockIdx.x * 4 + rt;
            #pragma unroll
            for (int nt = 0; nt < 4; ++nt) {
                float sA = 0.f;
                #pragma unroll
                for (int rg = 0; rg < 4; ++rg)
                    sA += fmaxf(acc[0][nt][rg] + bias[nt], 0.f)
                        + fmaxf(acc[1][nt][rg] + bias[nt], 0.f);
                sA = qsum(sA);
                if (lane < 16)
                    out[(size_t)bb * 192 + nt * 16 + lane] = sA;   // col = s-64
            }
        }
    }
    __syncthreads();   // NH (incl. pad zeros) visible to all waves

    #pragma unroll
    for (int mt = 0; mt < 2; ++mt)
        #pragma unroll
        for (int nt = 0; nt < 4; ++nt) acc[mt][nt] = zero4;

    // ========== phase 1: 81 tiles (80 real + pad), j from NH ==========
    gemm_phase<T1P, 1>(W1p, NH, 72, xi2, Wb, acc, tid);

    {   // epilogue 1: bias+relu; d-sum -> out[:, 64:192]
        float bias[4];
        #pragma unroll
        for (int nt = 0; nt < 4; ++nt) bias[nt] = b1[sh * 64 + nt * 16 + ml];
        int bb = blockIdx.x * 4 + rt;
        #pragma unroll
        for (int nt = 0; nt < 4; ++nt) {
            float sA = 0.f;
            #pragma unroll
            for (int rg = 0; rg < 4; ++rg)
                sA += fmaxf(acc[0][nt][rg] + bias[nt], 0.f)
                    + fmaxf(acc[1][nt][rg] + bias[nt], 0.f);
            sA = qsum(sA);
            if (lane < 16)
                out[(size_t)bb * 192 + 64 + sh * 64 + nt * 16 + lane] = sA;
        }
    }
}

extern "C" void kernel_launch(void* const* d_in, const int* in_sizes, int n_in,
                              void* d_out, int out_size, void* d_ws, size_t ws_size,
                              hipStream_t stream) {
    const float* x  = (const float*)d_in[0];   // [2048][40][32]
    const float* W0 = (const float*)d_in[1];   // [40][40][128]
    const float* b0 = (const float*)d_in[2];   // [128]
    const float* W1 = (const float*)d_in[3];   // [40][64][128]
    const float* b1 = (const float*)d_in[4];   // [128]
    float* out = (float*)d_out;                // [2048][192]

    unsigned short* W0p = (unsigned short*)d_ws;                          // T0*8192  = 245760 B
    unsigned short* W1p = (unsigned short*)((char*)d_ws + T0 * 4096 * 2); // T1P*8192 = 663552 B

    permute_w_both<<<T0 + T1P, 256, 0, stream>>>(W0, W1, W0p, W1p);
    fused_two_layer<<<512, 512, 0, stream>>>(x, W0p, b0, W1p, b1, out);
}